// Round 1
// baseline (243.054 us; speedup 1.0000x reference)
//
#include <hip/hip_runtime.h>
#include <math.h>

// NormalMixtureEM: B=16384 rows, L=512 samples, K=4 components, 5 EM iters.
// One wave (64 lanes) per row; lane i holds samples l = i + 64*j, j=0..7,
// entirely in registers. Reductions over L via __shfl_xor butterflies.
// data_var uses moment expansion S2 - 2*mu*S1 + mu^2*S0 (single pass).
// log_mix evaluated as quadratic A*x^2 + B*x + C in log2 domain.

constexpr int Bn = 16384;
constexpr int Ln = 512;
constexpr int Kn = 4;
constexpr int NITER = 5;
constexpr float EPSf = 1e-8f;
constexpr float NOISEf = 0.01f;
constexpr float LOG2E = 1.4426950408889634f;

__device__ __forceinline__ float wred(float v) {
#pragma unroll
    for (int m = 32; m >= 1; m >>= 1) v += __shfl_xor(v, m, 64);
    return v;
}

__global__ __launch_bounds__(256) void em_kernel(
    const float* __restrict__ windows,
    const float* __restrict__ centers,
    const float* __restrict__ scales,
    const float* __restrict__ iweights,
    const float* __restrict__ prior_p_param,
    const float* __restrict__ weights_param,
    const float* __restrict__ blend,
    const float* __restrict__ noise,
    float* __restrict__ out_g,
    float* __restrict__ out_w,
    float* __restrict__ out_mu,
    float* __restrict__ out_sigma)
{
    const int lane = threadIdx.x & 63;
    const int wv = threadIdx.x >> 6;
    const int b = blockIdx.x * 4 + wv;
    if (b >= Bn) return;

    const float* __restrict__ xr = windows + (size_t)b * Ln;
    float x[8], xx[8], wl[8];
#pragma unroll
    for (int j = 0; j < 8; ++j) {
        float v = xr[lane + 64 * j];
        x[j] = v;
        xx[j] = v * v;
        wl[j] = __expf(weights_param[lane + 64 * j]);  // exp(weights_param[l])
    }

    // Row stats: mean, unbiased var (ddof=1)
    float s = 0.f, ss = 0.f;
#pragma unroll
    for (int j = 0; j < 8; ++j) { s += x[j]; ss += xx[j]; }
    s = wred(s); ss = wred(ss);
    const float mean = s * (1.0f / Ln);
    float var1 = (ss - s * mean) * (1.0f / (Ln - 1));
    var1 = fmaxf(var1, 0.f);
    const float sd = sqrtf(var1);
    const float prior_var = var1;

    const float prior_p = 1.f / (1.f + __expf(-prior_p_param[0]));
    const float blender = 1.f / (1.f + __expf(-blend[0]));
    const float omb = 1.f - blender;

    const float4 nz = *(const float4*)(noise + (size_t)b * 4);
    const float nzv[4] = { nz.x, nz.y, nz.z, nz.w };

    // Initialize per-component params
    float mu[4], sig[4], w[4], inv_se[4];
#pragma unroll
    for (int k = 0; k < 4; ++k) {
        mu[k] = fmaf(centers[k], sd, mean) + nzv[k] * sd * NOISEf;
        sig[k] = fabsf(scales[k]) * sd;
        w[k] = iweights[k];
        inv_se[k] = 1.f / (sig[k] + EPSf);
    }

    for (int it = 0; it < NITER; ++it) {
        const bool last = (it == NITER - 1);
        // log_mix(x) = -0.5*((x-mu)*inv_se)^2 + log((w+EPS)*inv_se)
        //           -> (A*x^2 + B*x + C) in log2 units
        float A2[4], B2[4], C2[4];
#pragma unroll
        for (int k = 0; k < 4; ++k) {
            float is2 = inv_se[k] * inv_se[k];
            float lw2 = __log2f((w[k] + EPSf) * inv_se[k]);
            A2[k] = (-0.5f * LOG2E) * is2;
            B2[k] = (LOG2E * mu[k]) * is2;
            C2[k] = fmaf((-0.5f * LOG2E) * (mu[k] * mu[k]), is2, lw2);
        }

        float S0[4] = {0,0,0,0}, S1[4] = {0,0,0,0}, S2[4] = {0,0,0,0};
#pragma unroll
        for (int j = 0; j < 8; ++j) {
            float lm[4], e[4];
#pragma unroll
            for (int k = 0; k < 4; ++k)
                lm[k] = fmaf(A2[k], xx[j], fmaf(B2[k], x[j], C2[k]));
            float m = fmaxf(fmaxf(lm[0], lm[1]), fmaxf(lm[2], lm[3]));
            float esum = 0.f;
#pragma unroll
            for (int k = 0; k < 4; ++k) {
                e[k] = __builtin_amdgcn_exp2f(lm[k] - m);  // v_exp_f32
                esum += e[k];
            }
            float inv = 1.f / esum;
            float wls = wl[j] * inv;  // weights[l] / esum
#pragma unroll
            for (int k = 0; k < 4; ++k) {
                float wg = e[k] * wls;              // g*weights[l]
                S0[k] += wg;
                S1[k] = fmaf(wg, x[j], S1[k]);
                S2[k] = fmaf(wg, xx[j], S2[k]);
            }
            if (last) {
                // g of final E-step -> output, coalesced float4 per l
                float4 g4 = make_float4(e[0] * inv, e[1] * inv, e[2] * inv, e[3] * inv);
                *(float4*)(out_g + ((size_t)b * Ln + lane + 64 * j) * 4) = g4;
            }
        }
#pragma unroll
        for (int k = 0; k < 4; ++k) {
            S0[k] = wred(S0[k]);
            S1[k] = wred(S1[k]);
            S2[k] = wred(S2[k]);
        }

        // M-step
        float wn[4], wsum = 0.f;
#pragma unroll
        for (int k = 0; k < 4; ++k) {
            float sg = fmaxf(S0[k], EPSf);
            float dmu = S1[k] / sg;
            float mun = fmaf(blender, dmu, omb * mean);
            // sum wg*(x-mun)^2 = S2 - 2*mun*S1 + mun^2*S0
            float num = fmaf(mun * mun, S0[k], fmaf(-2.f * mun, S1[k], S2[k]));
            float dv = fmaxf(num / sg, 0.f);
            float var = fmaf(blender, dv, omb * prior_var);
            float sgn = sqrtf(var + EPSf);
            mu[k] = mun;
            sig[k] = sgn;
            inv_se[k] = 1.f / (sgn + EPSf);
            wn[k] = sg + prior_p;
            wsum += wn[k];
        }
        float invws = 1.f / wsum;
#pragma unroll
        for (int k = 0; k < 4; ++k) w[k] = wn[k] * invws;
    }

    if (lane == 0) {
        *(float4*)(out_w     + (size_t)b * 4) = make_float4(w[0], w[1], w[2], w[3]);
        *(float4*)(out_mu    + (size_t)b * 4) = make_float4(mu[0], mu[1], mu[2], mu[3]);
        *(float4*)(out_sigma + (size_t)b * 4) = make_float4(sig[0], sig[1], sig[2], sig[3]);
    }
}

extern "C" void kernel_launch(void* const* d_in, const int* in_sizes, int n_in,
                              void* d_out, int out_size, void* d_ws, size_t ws_size,
                              hipStream_t stream) {
    const float* windows       = (const float*)d_in[0];
    const float* init_centers  = (const float*)d_in[1];
    const float* init_scales   = (const float*)d_in[2];
    const float* init_weights  = (const float*)d_in[3];
    const float* prior_p_param = (const float*)d_in[4];
    const float* weights_param = (const float*)d_in[5];
    const float* blend         = (const float*)d_in[6];
    const float* noise         = (const float*)d_in[7];

    float* out       = (float*)d_out;
    float* out_g     = out;                                    // [B, L, K]
    float* out_w     = out_g + (size_t)Bn * Ln * Kn;           // [B, K]
    float* out_mu    = out_w + (size_t)Bn * Kn;                // [B, K]
    float* out_sigma = out_mu + (size_t)Bn * Kn;               // [B, K]

    dim3 grid(Bn / 4);   // 4 waves per block, 1 wave per row
    dim3 block(256);
    hipLaunchKernelGGL(em_kernel, grid, block, 0, stream,
                       windows, init_centers, init_scales, init_weights,
                       prior_p_param, weights_param, blend, noise,
                       out_g, out_w, out_mu, out_sigma);
}

// Round 2
// 218.464 us; speedup vs baseline: 1.1126x; 1.1126x over previous
//
#include <hip/hip_runtime.h>
#include <math.h>

// NormalMixtureEM: B=16384 rows, L=512, K=4, 5 EM iters.
// One wave per row; lane i holds samples l = i + 64*j, j=0..7, in registers.
// Reductions over L via __shfl_xor butterflies. Single-pass moments:
// sum wg*(x-mu)^2 = S2 - 2*mu*S1 + mu^2*S0. log_mix as quadratic in log2.
// R2: __launch_bounds__(256,4) to stop the backend squeezing to 60 VGPRs
// (spill); raw v_rcp for all divides; stable-softmax max removed (bounded:
// sigma >= sqrt(EPS) => lm in [-106, +14] log2 — no overflow/underflow).

constexpr int Bn = 16384;
constexpr int Ln = 512;
constexpr int Kn = 4;
constexpr int NITER = 5;
constexpr float EPSf = 1e-8f;
constexpr float NOISEf = 0.01f;
constexpr float LOG2E = 1.4426950408889634f;

__device__ __forceinline__ float wred(float v) {
#pragma unroll
    for (int m = 32; m >= 1; m >>= 1) v += __shfl_xor(v, m, 64);
    return v;
}

__device__ __forceinline__ float frcp(float v) { return __builtin_amdgcn_rcpf(v); }

struct RowState {
    float x[8], xx[8], wl[8];
    float mu[4], w[4], inv_se[4], sig[4];
    float mean, prior_var, blender, omb, prior_p;
};

template <bool LAST>
__device__ __forceinline__ void em_iter(RowState& st, float* __restrict__ gout, int lane) {
    // log_mix in log2 units: A*x^2 + B*x + C
    float A2[4], B2[4], C2[4];
#pragma unroll
    for (int k = 0; k < 4; ++k) {
        float is2 = st.inv_se[k] * st.inv_se[k];
        float lw2 = __log2f((st.w[k] + EPSf) * st.inv_se[k]);
        A2[k] = (-0.5f * LOG2E) * is2;
        B2[k] = (LOG2E * st.mu[k]) * is2;
        C2[k] = fmaf((-0.5f * LOG2E) * (st.mu[k] * st.mu[k]), is2, lw2);
    }

    float S0[4] = {0,0,0,0}, S1[4] = {0,0,0,0}, S2[4] = {0,0,0,0};
#pragma unroll
    for (int j = 0; j < 8; ++j) {
        float e[4];
        float esum = 0.f;
#pragma unroll
        for (int k = 0; k < 4; ++k) {
            float lm = fmaf(A2[k], st.xx[j], fmaf(B2[k], st.x[j], C2[k]));
            e[k] = __builtin_amdgcn_exp2f(lm);
            esum += e[k];
        }
        float inv = frcp(esum);
        float wls = st.wl[j] * inv;
#pragma unroll
        for (int k = 0; k < 4; ++k) {
            float wg = e[k] * wls;
            S0[k] += wg;
            S1[k] = fmaf(wg, st.x[j], S1[k]);
            S2[k] = fmaf(wg, st.xx[j], S2[k]);
        }
        if (LAST) {
            float4 g4 = make_float4(e[0] * inv, e[1] * inv, e[2] * inv, e[3] * inv);
            *(float4*)(gout + (size_t)(lane + 64 * j) * 4) = g4;
        }
    }
#pragma unroll
    for (int k = 0; k < 4; ++k) {
        S0[k] = wred(S0[k]);
        S1[k] = wred(S1[k]);
        S2[k] = wred(S2[k]);
    }

    // M-step
    float wn[4], wsum = 0.f;
#pragma unroll
    for (int k = 0; k < 4; ++k) {
        float sg = fmaxf(S0[k], EPSf);
        float rsg = frcp(sg);
        float dmu = S1[k] * rsg;
        float mun = fmaf(st.blender, dmu, st.omb * st.mean);
        float num = fmaf(mun * mun, S0[k], fmaf(-2.f * mun, S1[k], S2[k]));
        float dv = fmaxf(num * rsg, 0.f);
        float var = fmaf(st.blender, dv, st.omb * st.prior_var);
        float sgn = sqrtf(var + EPSf);
        st.mu[k] = mun;
        st.sig[k] = sgn;
        st.inv_se[k] = frcp(sgn + EPSf);
        wn[k] = sg + st.prior_p;
        wsum += wn[k];
    }
    float invws = frcp(wsum);
#pragma unroll
    for (int k = 0; k < 4; ++k) st.w[k] = wn[k] * invws;
}

__global__ __launch_bounds__(256, 4) void em_kernel(
    const float* __restrict__ windows,
    const float* __restrict__ centers,
    const float* __restrict__ scales,
    const float* __restrict__ iweights,
    const float* __restrict__ prior_p_param,
    const float* __restrict__ weights_param,
    const float* __restrict__ blend,
    const float* __restrict__ noise,
    float* __restrict__ out_g,
    float* __restrict__ out_w,
    float* __restrict__ out_mu,
    float* __restrict__ out_sigma)
{
    const int lane = threadIdx.x & 63;
    const int wv = threadIdx.x >> 6;
    const int b = blockIdx.x * 4 + wv;

    RowState st;
    const float* __restrict__ xr = windows + (size_t)b * Ln;
#pragma unroll
    for (int j = 0; j < 8; ++j) {
        float v = xr[lane + 64 * j];
        st.x[j] = v;
        st.xx[j] = v * v;
        st.wl[j] = __expf(weights_param[lane + 64 * j]);
    }

    float s = 0.f, ss = 0.f;
#pragma unroll
    for (int j = 0; j < 8; ++j) { s += st.x[j]; ss += st.xx[j]; }
    s = wred(s); ss = wred(ss);
    st.mean = s * (1.0f / Ln);
    float var1 = fmaxf((ss - s * st.mean) * (1.0f / (Ln - 1)), 0.f);
    const float sd = sqrtf(var1);
    st.prior_var = var1;

    st.prior_p = 1.f / (1.f + __expf(-prior_p_param[0]));
    st.blender = 1.f / (1.f + __expf(-blend[0]));
    st.omb = 1.f - st.blender;

    const float4 nz = *(const float4*)(noise + (size_t)b * 4);
    const float nzv[4] = { nz.x, nz.y, nz.z, nz.w };

#pragma unroll
    for (int k = 0; k < 4; ++k) {
        st.mu[k] = fmaf(centers[k], sd, st.mean) + nzv[k] * sd * NOISEf;
        float sg0 = fabsf(scales[k]) * sd;
        st.sig[k] = sg0;
        st.w[k] = iweights[k];
        st.inv_se[k] = frcp(sg0 + EPSf);
    }

    float* gout = out_g + (size_t)b * Ln * Kn;
    for (int it = 0; it < NITER - 1; ++it)
        em_iter<false>(st, gout, lane);
    em_iter<true>(st, gout, lane);

    if (lane == 0) {
        *(float4*)(out_w     + (size_t)b * 4) = make_float4(st.w[0], st.w[1], st.w[2], st.w[3]);
        *(float4*)(out_mu    + (size_t)b * 4) = make_float4(st.mu[0], st.mu[1], st.mu[2], st.mu[3]);
        *(float4*)(out_sigma + (size_t)b * 4) = make_float4(st.sig[0], st.sig[1], st.sig[2], st.sig[3]);
    }
}

extern "C" void kernel_launch(void* const* d_in, const int* in_sizes, int n_in,
                              void* d_out, int out_size, void* d_ws, size_t ws_size,
                              hipStream_t stream) {
    const float* windows       = (const float*)d_in[0];
    const float* init_centers  = (const float*)d_in[1];
    const float* init_scales   = (const float*)d_in[2];
    const float* init_weights  = (const float*)d_in[3];
    const float* prior_p_param = (const float*)d_in[4];
    const float* weights_param = (const float*)d_in[5];
    const float* blend         = (const float*)d_in[6];
    const float* noise         = (const float*)d_in[7];

    float* out       = (float*)d_out;
    float* out_g     = out;                                    // [B, L, K]
    float* out_w     = out_g + (size_t)Bn * Ln * Kn;           // [B, K]
    float* out_mu    = out_w + (size_t)Bn * Kn;                // [B, K]
    float* out_sigma = out_mu + (size_t)Bn * Kn;               // [B, K]

    dim3 grid(Bn / 4);   // 4 waves per block, 1 wave per row
    dim3 block(256);
    hipLaunchKernelGGL(em_kernel, grid, block, 0, stream,
                       windows, init_centers, init_scales, init_weights,
                       prior_p_param, weights_param, blend, noise,
                       out_g, out_w, out_mu, out_sigma);
}

// Round 4
// 213.834 us; speedup vs baseline: 1.1366x; 1.0216x over previous
//
#include <hip/hip_runtime.h>
#include <math.h>

// NormalMixtureEM: B=16384 rows, L=512, K=4, 5 EM iters.
// One wave per row; lane i holds samples l = i + 64*j, j=0..7, in registers.
// R4 (= R3 with dpp ctrl as template arg — builtin requires ICE):
//  - Wave reductions via DPP (row_shr 1/2/4/8 + row_bcast 15/31 + readlane 63)
//    instead of __shfl_xor: no LDS-pipe traffic, no lgkmcnt stall chains,
//    results become wave-uniform for the M-step.
//  - Component 3 moments derived from iteration-invariant totals
//    W{0,1,2} = sum_l wl*{1,x,x^2} (since sum_k g = 1), dropping k=3 from the
//    per-sample accumulate.
//  - Single-pass moments: sum wg*(x-mu)^2 = S2 - 2*mu*S1 + mu^2*S0.
//  - log_mix as quadratic A*x^2+B*x+C in log2 domain; raw v_rcp/v_exp.

constexpr int Bn = 16384;
constexpr int Ln = 512;
constexpr int Kn = 4;
constexpr int NITER = 5;
constexpr float EPSf = 1e-8f;
constexpr float NOISEf = 0.01f;
constexpr float LOG2E = 1.4426950408889634f;

__device__ __forceinline__ float frcp(float v) { return __builtin_amdgcn_rcpf(v); }

template <int CTRL>
__device__ __forceinline__ float dpp_add(float v) {
    int t = __builtin_amdgcn_update_dpp(0, __float_as_int(v), CTRL, 0xF, 0xF, true);
    return v + __int_as_float(t);
}

// Full-wave sum; returns wave-uniform total (readlane 63).
__device__ __forceinline__ float wred_total(float v) {
    v = dpp_add<0x111>(v);  // row_shr:1
    v = dpp_add<0x112>(v);  // row_shr:2
    v = dpp_add<0x114>(v);  // row_shr:4
    v = dpp_add<0x118>(v);  // row_shr:8
    v = dpp_add<0x142>(v);  // row_bcast:15
    v = dpp_add<0x143>(v);  // row_bcast:31
    return __int_as_float(__builtin_amdgcn_readlane(__float_as_int(v), 63));
}

struct RowState {
    float x[8], xx[8], wl[8];
    float mu[4], w[4], inv_se[4], sig[4];
    float mean, prior_var, blender, omb, prior_p;
    float W0, W1, W2;   // iteration-invariant: sum_l wl*{1, x, x^2}
};

template <bool LAST>
__device__ __forceinline__ void em_iter(RowState& st, float* __restrict__ gout, int lane) {
    // log_mix in log2 units: A*x^2 + B*x + C (wave-uniform coefficients)
    float A2[4], B2[4], C2[4];
#pragma unroll
    for (int k = 0; k < 4; ++k) {
        float is2 = st.inv_se[k] * st.inv_se[k];
        float lw2 = __log2f((st.w[k] + EPSf) * st.inv_se[k]);
        A2[k] = (-0.5f * LOG2E) * is2;
        B2[k] = (LOG2E * st.mu[k]) * is2;
        C2[k] = fmaf((-0.5f * LOG2E) * (st.mu[k] * st.mu[k]), is2, lw2);
    }

    float S0[3] = {0,0,0}, S1[3] = {0,0,0}, S2[3] = {0,0,0};
#pragma unroll
    for (int j = 0; j < 8; ++j) {
        float e[4];
        float esum = 0.f;
#pragma unroll
        for (int k = 0; k < 4; ++k) {
            float lm = fmaf(A2[k], st.xx[j], fmaf(B2[k], st.x[j], C2[k]));
            e[k] = __builtin_amdgcn_exp2f(lm);
            esum += e[k];
        }
        float inv = frcp(esum);
        float wls = st.wl[j] * inv;
        float wlsx = wls * st.x[j];
        float wlsxx = wls * st.xx[j];
#pragma unroll
        for (int k = 0; k < 3; ++k) {
            S0[k] = fmaf(e[k], wls,   S0[k]);
            S1[k] = fmaf(e[k], wlsx,  S1[k]);
            S2[k] = fmaf(e[k], wlsxx, S2[k]);
        }
        if (LAST) {
            float4 g4 = make_float4(e[0] * inv, e[1] * inv, e[2] * inv, e[3] * inv);
            *(float4*)(gout + (size_t)(lane + 64 * j) * 4) = g4;
        }
    }

    // Reduce 9 moments (DPP, wave-uniform results); derive component 3.
    float T0[4], T1[4], T2[4];
#pragma unroll
    for (int k = 0; k < 3; ++k) {
        T0[k] = wred_total(S0[k]);
        T1[k] = wred_total(S1[k]);
        T2[k] = wred_total(S2[k]);
    }
    T0[3] = st.W0 - T0[0] - T0[1] - T0[2];
    T1[3] = st.W1 - T1[0] - T1[1] - T1[2];
    T2[3] = st.W2 - T2[0] - T2[1] - T2[2];

    // M-step (wave-uniform)
    float wn[4], wsum = 0.f;
#pragma unroll
    for (int k = 0; k < 4; ++k) {
        float sg = fmaxf(T0[k], EPSf);
        float rsg = frcp(sg);
        float dmu = T1[k] * rsg;
        float mun = fmaf(st.blender, dmu, st.omb * st.mean);
        float num = fmaf(mun * mun, T0[k], fmaf(-2.f * mun, T1[k], T2[k]));
        float dv = fmaxf(num * rsg, 0.f);
        float var = fmaf(st.blender, dv, st.omb * st.prior_var);
        float sgn = sqrtf(var + EPSf);
        st.mu[k] = mun;
        st.sig[k] = sgn;
        st.inv_se[k] = frcp(sgn + EPSf);
        wn[k] = sg + st.prior_p;
        wsum += wn[k];
    }
    float invws = frcp(wsum);
#pragma unroll
    for (int k = 0; k < 4; ++k) st.w[k] = wn[k] * invws;
}

__global__ __launch_bounds__(256, 4) void em_kernel(
    const float* __restrict__ windows,
    const float* __restrict__ centers,
    const float* __restrict__ scales,
    const float* __restrict__ iweights,
    const float* __restrict__ prior_p_param,
    const float* __restrict__ weights_param,
    const float* __restrict__ blend,
    const float* __restrict__ noise,
    float* __restrict__ out_g,
    float* __restrict__ out_w,
    float* __restrict__ out_mu,
    float* __restrict__ out_sigma)
{
    const int lane = threadIdx.x & 63;
    const int wv = threadIdx.x >> 6;
    const int b = blockIdx.x * 4 + wv;

    RowState st;
    const float* __restrict__ xr = windows + (size_t)b * Ln;
#pragma unroll
    for (int j = 0; j < 8; ++j) {
        float v = xr[lane + 64 * j];
        st.x[j] = v;
        st.xx[j] = v * v;
        st.wl[j] = __expf(weights_param[lane + 64 * j]);
    }

    // Row stats + iteration-invariant weighted totals, all via DPP.
    float s = 0.f, ss = 0.f, w0 = 0.f, w1 = 0.f, w2 = 0.f;
#pragma unroll
    for (int j = 0; j < 8; ++j) {
        s += st.x[j];
        ss += st.xx[j];
        w0 += st.wl[j];
        w1 = fmaf(st.wl[j], st.x[j], w1);
        w2 = fmaf(st.wl[j], st.xx[j], w2);
    }
    s = wred_total(s);
    ss = wred_total(ss);
    st.W0 = wred_total(w0);
    st.W1 = wred_total(w1);
    st.W2 = wred_total(w2);

    st.mean = s * (1.0f / Ln);
    float var1 = fmaxf((ss - s * st.mean) * (1.0f / (Ln - 1)), 0.f);
    const float sd = sqrtf(var1);
    st.prior_var = var1;

    st.prior_p = 1.f / (1.f + __expf(-prior_p_param[0]));
    st.blender = 1.f / (1.f + __expf(-blend[0]));
    st.omb = 1.f - st.blender;

    const float4 nz = *(const float4*)(noise + (size_t)b * 4);
    const float nzv[4] = { nz.x, nz.y, nz.z, nz.w };

#pragma unroll
    for (int k = 0; k < 4; ++k) {
        st.mu[k] = fmaf(centers[k], sd, st.mean) + nzv[k] * sd * NOISEf;
        float sg0 = fabsf(scales[k]) * sd;
        st.sig[k] = sg0;
        st.w[k] = iweights[k];
        st.inv_se[k] = frcp(sg0 + EPSf);
    }

    float* gout = out_g + (size_t)b * Ln * Kn;
    for (int it = 0; it < NITER - 1; ++it)
        em_iter<false>(st, gout, lane);
    em_iter<true>(st, gout, lane);

    if (lane == 0) {
        *(float4*)(out_w     + (size_t)b * 4) = make_float4(st.w[0], st.w[1], st.w[2], st.w[3]);
        *(float4*)(out_mu    + (size_t)b * 4) = make_float4(st.mu[0], st.mu[1], st.mu[2], st.mu[3]);
        *(float4*)(out_sigma + (size_t)b * 4) = make_float4(st.sig[0], st.sig[1], st.sig[2], st.sig[3]);
    }
}

extern "C" void kernel_launch(void* const* d_in, const int* in_sizes, int n_in,
                              void* d_out, int out_size, void* d_ws, size_t ws_size,
                              hipStream_t stream) {
    const float* windows       = (const float*)d_in[0];
    const float* init_centers  = (const float*)d_in[1];
    const float* init_scales   = (const float*)d_in[2];
    const float* init_weights  = (const float*)d_in[3];
    const float* prior_p_param = (const float*)d_in[4];
    const float* weights_param = (const float*)d_in[5];
    const float* blend         = (const float*)d_in[6];
    const float* noise         = (const float*)d_in[7];

    float* out       = (float*)d_out;
    float* out_g     = out;                                    // [B, L, K]
    float* out_w     = out_g + (size_t)Bn * Ln * Kn;           // [B, K]
    float* out_mu    = out_w + (size_t)Bn * Kn;                // [B, K]
    float* out_sigma = out_mu + (size_t)Bn * Kn;               // [B, K]

    dim3 grid(Bn / 4);   // 4 waves per block, 1 wave per row
    dim3 block(256);
    hipLaunchKernelGGL(em_kernel, grid, block, 0, stream,
                       windows, init_centers, init_scales, init_weights,
                       prior_p_param, weights_param, blend, noise,
                       out_g, out_w, out_mu, out_sigma);
}